// Round 11
// baseline (384.782 us; speedup 1.0000x reference)
//
#include <hip/hip_runtime.h>
#include <hip/hip_fp16.h>

#define N_NODES 100000
#define N_EDGES 800000
#define DIM 64
#define BN_EPS 1e-5f
#define LDX 68   // sX row stride (floats): 16B-aligned, 2-way banks (free)
#define EDGE_CAP 1600000

// ===========================================================================
// Gather buffers (xh, hbuf*) use a ZERO-ROW layout: row 0 = zeros, node r at
// row r+1, values pre-scaled by dinv[r] (y = dinv*x). CSR stores src+1 (4 B);
// pad entries are 0 (memset) and gather zeros. Agg[n] = dinv[n]*(y[n]+sum y).
// ===========================================================================

// Merged: x (f32) -> xh rows 1..N (fp16, unscaled yet) + zero row 0 + degree count.
__global__ __launch_bounds__(256) void k_cvt_count(const float* __restrict__ x,
                                                   __half* __restrict__ xh,
                                                   const int* __restrict__ dst,
                                                   int* __restrict__ deg) {
    int idx = blockIdx.x * blockDim.x + threadIdx.x;
    if (idx < 1600000) {
        float4 v = ((const float4*)x)[idx];
        unsigned int u0 = __half_as_ushort(__float2half(v.x));
        unsigned int u1 = __half_as_ushort(__float2half(v.y));
        unsigned int u2 = __half_as_ushort(__float2half(v.z));
        unsigned int u3 = __half_as_ushort(__float2half(v.w));
        ((uint2*)(xh + DIM))[idx] = make_uint2(u0 | (u1 << 16), u2 | (u3 << 16));
    }
    if (blockIdx.x == 0 && threadIdx.x < 16)
        ((uint2*)xh)[threadIdx.x] = make_uint2(0u, 0u);   // zero row 0
    if (idx < N_EDGES) atomicAdd(&deg[dst[idx]], 1);
}

// Merged scan + tail-weight algebra.
// Blocks 0..97: block-local scan of padded degrees + atomic global base;
// writes row_off, cursor, dinv. Block 98: W3p = W3@pW1, b3p = b3@pW1+pb1.
__global__ __launch_bounds__(256) void k_scan_fuse(const int* __restrict__ deg,
                                                   int* __restrict__ row_off,
                                                   int* __restrict__ cursor,
                                                   float* __restrict__ dinv,
                                                   int* __restrict__ gcount,
                                                   const float* __restrict__ W3,
                                                   const float* __restrict__ b3,
                                                   const float* __restrict__ pW1,
                                                   const float* __restrict__ pb1,
                                                   float* __restrict__ W3p,
                                                   float* __restrict__ b3p) {
    int tid = threadIdx.x;
    if (blockIdx.x == 98) {
        int c = tid & 63;
        int kbase = (tid >> 6) * 16;
        for (int k = kbase; k < kbase + 16; ++k) {
            float acc = 0.f;
#pragma unroll 8
            for (int j = 0; j < 64; ++j)
                acc = fmaf(W3[k * 64 + j], pW1[j * 64 + c], acc);
            W3p[k * 64 + c] = acc;
        }
        if (tid < 64) {
            float acc = pb1[c];
#pragma unroll 8
            for (int j = 0; j < 64; ++j)
                acc = fmaf(b3[j], pW1[j * 64 + c], acc);
            b3p[c] = acc;
        }
        return;
    }
    __shared__ int sdata[256];
    __shared__ int sbase;
    int base = blockIdx.x * 1024 + tid * 4;
    int4 d = make_int4(0, 0, 0, 0);
    int4 v = make_int4(0, 0, 0, 0);
    if (base < N_NODES) {
        d = *(const int4*)(deg + base);   // N % 4 == 0
        v.x = (d.x + 7) & ~7;
        v.y = (d.y + 7) & ~7;
        v.z = (d.z + 7) & ~7;
        v.w = (d.w + 7) & ~7;
    }
    int tsum = v.x + v.y + v.z + v.w;
    sdata[tid] = tsum;
    __syncthreads();
    for (int off = 1; off < 256; off <<= 1) {
        int t = (tid >= off) ? sdata[tid - off] : 0;
        __syncthreads();
        sdata[tid] += t;
        __syncthreads();
    }
    if (tid == 255) sbase = atomicAdd(gcount, sdata[255]);
    __syncthreads();
    if (base >= N_NODES) return;
    int excl = sdata[tid] - tsum + sbase;
    int4 o;
    o.x = excl;
    o.y = o.x + v.x;
    o.z = o.y + v.y;
    o.w = o.z + v.z;
    *(int4*)(row_off + base) = o;
    *(int4*)(cursor + base) = o;
    float4 di;
    di.x = rsqrtf((float)(d.x + 1));
    di.y = rsqrtf((float)(d.y + 1));
    di.z = rsqrtf((float)(d.z + 1));
    di.w = rsqrtf((float)(d.w + 1));
    *(float4*)(dinv + base) = di;
}

// Merged: CSR scatter (blocks 0..3124) + xh *= dinv scaling (blocks 3125..9374).
// Both depend only on k_scan_fuse; independent of each other.
__global__ __launch_bounds__(256) void k_build_scale(const int* __restrict__ ei,
                                                     int* __restrict__ cursor,
                                                     int* __restrict__ edges,
                                                     const float* __restrict__ dinv,
                                                     __half* __restrict__ xh) {
    int b = blockIdx.x;
    int tid = threadIdx.x;
    if (b < 3125) {
        int e = b * 256 + tid;
        if (e >= N_EDGES) return;
        int s = ei[e];
        int d = ei[N_EDGES + e];
        int pos = atomicAdd(&cursor[d], 1);
        edges[pos] = s + 1;                  // shifted index (row 0 = zeros)
    } else {
        int idx = (b - 3125) * 256 + tid;    // uint2 index over N*64 halfs
        int row = idx >> 4;                  // node (16 uint2 per row)
        float dv = dinv[row];
        uint2 u = ((uint2*)(xh + DIM))[idx];
        float f0 = __half2float(__ushort_as_half((unsigned short)(u.x & 0xffff))) * dv;
        float f1 = __half2float(__ushort_as_half((unsigned short)(u.x >> 16))) * dv;
        float f2 = __half2float(__ushort_as_half((unsigned short)(u.y & 0xffff))) * dv;
        float f3 = __half2float(__ushort_as_half((unsigned short)(u.y >> 16))) * dv;
        unsigned int u0 = __half_as_ushort(__float2half(f0));
        unsigned int u1 = __half_as_ushort(__float2half(f1));
        unsigned int u2 = __half_as_ushort(__float2half(f2));
        unsigned int u3 = __half_as_ushort(__float2half(f3));
        ((uint2*)(xh + DIM))[idx] = make_uint2(u0 | (u1 << 16), u2 | (u3 << 16));
    }
}

// ===========================================================================
// Aggregation: one wave per node, lane = column. Weightless gather of
// pre-scaled rows: out[n] = dinv[n] * (y[n] + sum_e y[edges[e]]).
// xin is the SHIFTED buffer base; out (abuf) is unshifted true-Agg fp16.
// ===========================================================================
__global__ __launch_bounds__(256) void k_aggregate(const __half* __restrict__ xin,
                                                   const int* __restrict__ row_off,
                                                   const int* __restrict__ deg,
                                                   const int* __restrict__ edges,
                                                   const float* __restrict__ dinv,
                                                   __half* __restrict__ out) {
    int lane = threadIdx.x & 63;
    int node = blockIdx.x * 4 + (threadIdx.x >> 6);   // grid = 25000 exact
    float acc = __half2float(xin[(size_t)(node + 1) * DIM + lane]);   // y[n]
    int beg = __builtin_amdgcn_readfirstlane(row_off[node]);
    int lenp = (__builtin_amdgcn_readfirstlane(deg[node]) + 7) & ~7;
    int end = beg + lenp;
    for (int k = beg; k < end; k += 8) {
        int e0 = edges[k + 0];
        int e1 = edges[k + 1];
        int e2 = edges[k + 2];
        int e3 = edges[k + 3];
        int e4 = edges[k + 4];
        int e5 = edges[k + 5];
        int e6 = edges[k + 6];
        int e7 = edges[k + 7];
        float v0 = __half2float(xin[(size_t)e0 * DIM + lane]);
        float v1 = __half2float(xin[(size_t)e1 * DIM + lane]);
        float v2 = __half2float(xin[(size_t)e2 * DIM + lane]);
        float v3 = __half2float(xin[(size_t)e3 * DIM + lane]);
        float v4 = __half2float(xin[(size_t)e4 * DIM + lane]);
        float v5 = __half2float(xin[(size_t)e5 * DIM + lane]);
        float v6 = __half2float(xin[(size_t)e6 * DIM + lane]);
        float v7 = __half2float(xin[(size_t)e7 * DIM + lane]);
        acc += ((v0 + v1) + (v2 + v3)) + ((v4 + v5) + (v6 + v7));
    }
    out[(size_t)node * DIM + lane] = __float2half(dinv[node] * acc);
}

// 64 FMAs of a 4-row x 4-col x 4-k outer-product step (sX stride = LDX)
#define GEMM_STEP(SX, SW)                                                      \
    {                                                                          \
        float4 a0 = *(const float4*)&SX[(r0 + 0) * LDX + k4 * 4];              \
        float4 a1 = *(const float4*)&SX[(r0 + 1) * LDX + k4 * 4];              \
        float4 a2 = *(const float4*)&SX[(r0 + 2) * LDX + k4 * 4];              \
        float4 a3 = *(const float4*)&SX[(r0 + 3) * LDX + k4 * 4];              \
        float4 b0 = *(const float4*)&SW[(k4 * 4 + 0) * 64 + c0];               \
        float4 b1 = *(const float4*)&SW[(k4 * 4 + 1) * 64 + c0];               \
        float4 b2 = *(const float4*)&SW[(k4 * 4 + 2) * 64 + c0];               \
        float4 b3 = *(const float4*)&SW[(k4 * 4 + 3) * 64 + c0];               \
        const float* ap[4] = {&a0.x, &a1.x, &a2.x, &a3.x};                     \
        _Pragma("unroll") for (int i = 0; i < 4; ++i) {                        \
            float x0 = ap[i][0], x1 = ap[i][1], x2 = ap[i][2], x3 = ap[i][3];  \
            acc[i][0] = fmaf(x0, b0.x, acc[i][0]);                             \
            acc[i][1] = fmaf(x0, b0.y, acc[i][1]);                             \
            acc[i][2] = fmaf(x0, b0.z, acc[i][2]);                             \
            acc[i][3] = fmaf(x0, b0.w, acc[i][3]);                             \
            acc[i][0] = fmaf(x1, b1.x, acc[i][0]);                             \
            acc[i][1] = fmaf(x1, b1.y, acc[i][1]);                             \
            acc[i][2] = fmaf(x1, b1.z, acc[i][2]);                             \
            acc[i][3] = fmaf(x1, b1.w, acc[i][3]);                             \
            acc[i][0] = fmaf(x2, b2.x, acc[i][0]);                             \
            acc[i][1] = fmaf(x2, b2.y, acc[i][1]);                             \
            acc[i][2] = fmaf(x2, b2.z, acc[i][2]);                             \
            acc[i][3] = fmaf(x2, b2.w, acc[i][3]);                             \
            acc[i][0] = fmaf(x3, b3.x, acc[i][0]);                             \
            acc[i][1] = fmaf(x3, b3.y, acc[i][1]);                             \
            acc[i][2] = fmaf(x3, b3.z, acc[i][2]);                             \
            acc[i][3] = fmaf(x3, b3.w, acc[i][3]);                             \
        }                                                                      \
    }

// stage one 64-row fp16 tile (unshifted) into fp32 LDS
#define STAGE_H2F(SRCPTR, SXPTR)                                               \
    {                                                                          \
        int r = tid >> 2;                                                      \
        int q = tid & 3;                                                       \
        int row = row0 + r;                                                    \
        float4* dst = (float4*)(SXPTR + r * LDX);                              \
        if (row < N_NODES) {                                                   \
            const uint2* src = (const uint2*)(SRCPTR + (size_t)row * DIM);     \
            _Pragma("unroll") for (int m = 0; m < 4; ++m) {                    \
                uint2 u = src[q + m * 4];                                      \
                float4 f;                                                      \
                f.x = __half2float(__ushort_as_half((unsigned short)(u.x & 0xffff)));       \
                f.y = __half2float(__ushort_as_half((unsigned short)(u.x >> 16)));          \
                f.z = __half2float(__ushort_as_half((unsigned short)(u.y & 0xffff)));       \
                f.w = __half2float(__ushort_as_half((unsigned short)(u.y >> 16)));          \
                dst[q + m * 4] = f;                                            \
            }                                                                  \
        } else {                                                               \
            float4 z = make_float4(0.f, 0.f, 0.f, 0.f);                        \
            _Pragma("unroll") for (int m = 0; m < 4; ++m) dst[q + m * 4] = z;  \
        }                                                                      \
    }

// ===========================================================================
// Register-tiled GEMM + BN + ReLU: fp16 in (unshifted), fp16 out SHIFTED and
// pre-scaled by dinv[row] (y' for the next gather). Zeroes out row 0.
// ===========================================================================
__global__ __launch_bounds__(256) void k_gemm_bn_h(const __half* __restrict__ xin,
                                                   const float* __restrict__ W,
                                                   const float* __restrict__ bias,
                                                   const float* __restrict__ bng,
                                                   const float* __restrict__ bnb,
                                                   const float* __restrict__ bnm,
                                                   const float* __restrict__ bnv,
                                                   const float* __restrict__ dinv,
                                                   __half* __restrict__ out) {
    __shared__ float sW[4096];
    __shared__ float sX[64 * LDX];
    int tid = threadIdx.x;
    int row0 = blockIdx.x * 64;

    if (blockIdx.x == 0 && tid < 16)
        ((uint2*)out)[tid] = make_uint2(0u, 0u);   // zero row 0

    for (int i = tid; i < 1024; i += 256)
        ((float4*)sW)[i] = ((const float4*)W)[i];
    STAGE_H2F(xin, sX)
    __syncthreads();

    int cq = tid & 15, rq = tid >> 4;
    int c0 = cq * 4, r0 = rq * 4;
    float acc[4][4];
#pragma unroll
    for (int i = 0; i < 4; ++i)
#pragma unroll
        for (int j = 0; j < 4; ++j) acc[i][j] = 0.f;

#pragma unroll 4
    for (int k4 = 0; k4 < 16; ++k4) GEMM_STEP(sX, sW)

    float4 bv = *(const float4*)&bias[c0];
    float4 g = *(const float4*)&bng[c0];
    float4 bb = *(const float4*)&bnb[c0];
    float4 m = *(const float4*)&bnm[c0];
    float4 vv = *(const float4*)&bnv[c0];
    float A0 = g.x * rsqrtf(vv.x + BN_EPS);
    float A1 = g.y * rsqrtf(vv.y + BN_EPS);
    float A2 = g.z * rsqrtf(vv.z + BN_EPS);
    float A3 = g.w * rsqrtf(vv.w + BN_EPS);
    float B0 = (bv.x - m.x) * A0 + bb.x;
    float B1 = (bv.y - m.y) * A1 + bb.y;
    float B2 = (bv.z - m.z) * A2 + bb.z;
    float B3 = (bv.w - m.w) * A3 + bb.w;
#pragma unroll
    for (int i = 0; i < 4; ++i) {
        int row = row0 + r0 + i;
        if (row >= N_NODES) break;
        float dv = dinv[row];
        unsigned int u0 = __half_as_ushort(__float2half(fmaxf(0.f, fmaf(acc[i][0], A0, B0)) * dv));
        unsigned int u1 = __half_as_ushort(__float2half(fmaxf(0.f, fmaf(acc[i][1], A1, B1)) * dv));
        unsigned int u2 = __half_as_ushort(__float2half(fmaxf(0.f, fmaf(acc[i][2], A2, B2)) * dv));
        unsigned int u3 = __half_as_ushort(__float2half(fmaxf(0.f, fmaf(acc[i][3], A3, B3)) * dv));
        *(uint2*)(out + (size_t)(row + 1) * DIM + c0) = make_uint2(u0 | (u1 << 16), u2 | (u3 << 16));
    }
}

// ===========================================================================
// Tail: out = tanh(x @ W3p + b3p) @ pW2 + pb2; fp16 in (unshifted), fp32 out.
// ===========================================================================
__global__ __launch_bounds__(256) void k_tail(const __half* __restrict__ xin,
                                              const float* __restrict__ W3p,
                                              const float* __restrict__ b3p,
                                              const float* __restrict__ pW2,
                                              const float* __restrict__ pb2,
                                              float* __restrict__ out) {
    __shared__ float sW1[4096];
    __shared__ float sW2[4096];
    __shared__ float sX[64 * LDX];
    int tid = threadIdx.x;
    int row0 = blockIdx.x * 64;

    for (int i = tid; i < 1024; i += 256) {
        ((float4*)sW1)[i] = ((const float4*)W3p)[i];
        ((float4*)sW2)[i] = ((const float4*)pW2)[i];
    }
    STAGE_H2F(xin, sX)
    __syncthreads();

    int cq = tid & 15, rq = tid >> 4;
    int c0 = cq * 4, r0 = rq * 4;
    float acc[4][4];

    // ---- GEMM 1: sX @ W3p ----
#pragma unroll
    for (int i = 0; i < 4; ++i)
#pragma unroll
        for (int j = 0; j < 4; ++j) acc[i][j] = 0.f;
#pragma unroll 4
    for (int k4 = 0; k4 < 16; ++k4) GEMM_STEP(sX, sW1)
    __syncthreads();

    {
        float4 bv = *(const float4*)&b3p[c0];
#pragma unroll
        for (int i = 0; i < 4; ++i) {
            float4 h;
            h.x = tanhf(acc[i][0] + bv.x);
            h.y = tanhf(acc[i][1] + bv.y);
            h.z = tanhf(acc[i][2] + bv.z);
            h.w = tanhf(acc[i][3] + bv.w);
            *(float4*)&sX[(r0 + i) * LDX + c0] = h;
        }
    }
    __syncthreads();

    // ---- GEMM 2: sX @ pW2 ----
#pragma unroll
    for (int i = 0; i < 4; ++i)
#pragma unroll
        for (int j = 0; j < 4; ++j) acc[i][j] = 0.f;
#pragma unroll 4
    for (int k4 = 0; k4 < 16; ++k4) GEMM_STEP(sX, sW2)

    float4 bv = *(const float4*)&pb2[c0];
#pragma unroll
    for (int i = 0; i < 4; ++i) {
        int row = row0 + r0 + i;
        if (row >= N_NODES) break;
        float4 o;
        o.x = acc[i][0] + bv.x;
        o.y = acc[i][1] + bv.y;
        o.z = acc[i][2] + bv.z;
        o.w = acc[i][3] + bv.w;
        *(float4*)(out + (size_t)row * DIM + c0) = o;
    }
}

// ===========================================================================
extern "C" void kernel_launch(void* const* d_in, const int* in_sizes, int n_in,
                              void* d_out, int out_size, void* d_ws, size_t ws_size,
                              hipStream_t stream) {
    const float* x     = (const float*)d_in[0];
    const int*   ei    = (const int*)d_in[1];
    const float* W1    = (const float*)d_in[2];
    const float* b1    = (const float*)d_in[3];
    const float* W2    = (const float*)d_in[4];
    const float* b2    = (const float*)d_in[5];
    const float* W3    = (const float*)d_in[6];
    const float* b3    = (const float*)d_in[7];
    const float* bn1_g = (const float*)d_in[8];
    const float* bn1_b = (const float*)d_in[9];
    const float* bn1_m = (const float*)d_in[10];
    const float* bn1_v = (const float*)d_in[11];
    const float* bn2_g = (const float*)d_in[12];
    const float* bn2_b = (const float*)d_in[13];
    const float* bn2_m = (const float*)d_in[14];
    const float* bn2_v = (const float*)d_in[15];
    const float* pW1   = (const float*)d_in[16];
    const float* pb1   = (const float*)d_in[17];
    const float* pW2   = (const float*)d_in[18];
    const float* pb2   = (const float*)d_in[19];
    float* out = (float*)d_out;

    // Layout: deg..edges contiguous so ONE memset zeroes deg, gcount, row_off,
    // cursor (overwritten by scan) and all edge pad slots (src=0 -> zero row).
    char* ws = (char*)d_ws;
    int*    deg     = (int*)ws;                      ws += 100352 * 4;
    int*    gcount  = (int*)ws;                      ws += 4 * 4;
    int*    row_off = (int*)ws;                      ws += 100352 * 4;
    int*    cursor  = (int*)ws;                      ws += 100352 * 4;
    int*    edges   = (int*)ws;                      ws += (size_t)EDGE_CAP * 4;
    float*  dinv    = (float*)ws;                    ws += 100352 * 4;
    float*  W3p     = (float*)ws;                    ws += 4096 * 4;
    float*  b3p     = (float*)ws;                    ws += 64 * 4;
    __half* xh      = (__half*)ws;                   ws += (size_t)(N_NODES + 4) * DIM * 2; // shifted
    __half* hbufA   = (__half*)ws;                   ws += (size_t)(N_NODES + 4) * DIM * 2; // shifted
    __half* hbufB   = (__half*)ws;                   ws += (size_t)(N_NODES + 4) * DIM * 2; // shifted
    __half* abuf    = (__half*)ws;                   ws += (size_t)N_NODES * DIM * 2;       // unshifted

    const int blk = 256;
    int gCvt  = 6250;                            // covers 1.6M cvt + 800k count
    int gBS   = 3125 + 6250;                     // build (3125) + scale (6250)
    int gAgg  = N_NODES / 4;                     // 25000 (exact)
    int gTile = (N_NODES + 63) / 64;             // 1563

    size_t zbytes = (size_t)(100352 * 3 + 4) * 4 + (size_t)EDGE_CAP * 4;
    hipMemsetAsync(deg, 0, zbytes, stream);
    k_cvt_count<<<gCvt, blk, 0, stream>>>(x, xh, ei + N_EDGES, deg);
    k_scan_fuse<<<99, blk, 0, stream>>>(deg, row_off, cursor, dinv, gcount,
                                        W3, b3, pW1, pb1, W3p, b3p);
    k_build_scale<<<gBS, blk, 0, stream>>>(ei, cursor, edges, dinv, xh);

    // ---- layer 1 ----
    k_aggregate<<<gAgg, blk, 0, stream>>>(xh, row_off, deg, edges, dinv, abuf);
    k_gemm_bn_h<<<gTile, blk, 0, stream>>>(abuf, W1, b1, bn1_g, bn1_b, bn1_m, bn1_v, dinv, hbufA);

    // ---- layer 2 ----
    k_aggregate<<<gAgg, blk, 0, stream>>>(hbufA, row_off, deg, edges, dinv, abuf);
    k_gemm_bn_h<<<gTile, blk, 0, stream>>>(abuf, W2, b2, bn2_g, bn2_b, bn2_m, bn2_v, dinv, hbufB);

    // ---- layer 3 + fused predictor ----
    k_aggregate<<<gAgg, blk, 0, stream>>>(hbufB, row_off, deg, edges, dinv, abuf);
    k_tail<<<gTile, blk, 0, stream>>>(abuf, W3p, b3p, pW2, pb2, out);
}

// Round 12
// 368.924 us; speedup vs baseline: 1.0430x; 1.0430x over previous
//
#include <hip/hip_runtime.h>
#include <hip/hip_fp16.h>

#define N_NODES 100000
#define N_EDGES 800000
#define DIM 64
#define BN_EPS 1e-5f
#define LDX 68   // sX row stride (floats): 16B-aligned, 2-way banks (free)
#define EDGE_CAP 1600000

// ===========================================================================
// Merged: x (f32) -> xh (fp16) conversion  +  in-degree count.
// ===========================================================================
__global__ __launch_bounds__(256) void k_cvt_count(const float* __restrict__ x,
                                                   __half* __restrict__ xh,
                                                   const int* __restrict__ dst,
                                                   int* __restrict__ deg) {
    int idx = blockIdx.x * blockDim.x + threadIdx.x;
    if (idx < 1600000) {
        float4 v = ((const float4*)x)[idx];
        unsigned int u0 = __half_as_ushort(__float2half(v.x));
        unsigned int u1 = __half_as_ushort(__float2half(v.y));
        unsigned int u2 = __half_as_ushort(__float2half(v.z));
        unsigned int u3 = __half_as_ushort(__float2half(v.w));
        ((uint2*)xh)[idx] = make_uint2(u0 | (u1 << 16), u2 | (u3 << 16));
    }
    if (idx < N_EDGES) atomicAdd(&deg[dst[idx]], 1);
}

// ===========================================================================
// Merged scan + tail-weight algebra.
// Blocks 0..97: block-local scan of padded degrees + atomic global base;
// writes row_off, cursor, dinv. Block 98: W3p = W3@pW1, b3p = b3@pW1+pb1.
// ===========================================================================
__global__ __launch_bounds__(256) void k_scan_fuse(const int* __restrict__ deg,
                                                   int* __restrict__ row_off,
                                                   int* __restrict__ cursor,
                                                   float* __restrict__ dinv,
                                                   int* __restrict__ gcount,
                                                   const float* __restrict__ W3,
                                                   const float* __restrict__ b3,
                                                   const float* __restrict__ pW1,
                                                   const float* __restrict__ pb1,
                                                   float* __restrict__ W3p,
                                                   float* __restrict__ b3p) {
    int tid = threadIdx.x;
    if (blockIdx.x == 98) {
        int c = tid & 63;
        int kbase = (tid >> 6) * 16;
        for (int k = kbase; k < kbase + 16; ++k) {
            float acc = 0.f;
#pragma unroll 8
            for (int j = 0; j < 64; ++j)
                acc = fmaf(W3[k * 64 + j], pW1[j * 64 + c], acc);
            W3p[k * 64 + c] = acc;
        }
        if (tid < 64) {
            float acc = pb1[c];
#pragma unroll 8
            for (int j = 0; j < 64; ++j)
                acc = fmaf(b3[j], pW1[j * 64 + c], acc);
            b3p[c] = acc;
        }
        return;
    }
    __shared__ int sdata[256];
    __shared__ int sbase;
    int base = blockIdx.x * 1024 + tid * 4;
    int4 d = make_int4(0, 0, 0, 0);
    int4 v = make_int4(0, 0, 0, 0);
    if (base < N_NODES) {
        d = *(const int4*)(deg + base);   // N % 4 == 0
        v.x = (d.x + 7) & ~7;
        v.y = (d.y + 7) & ~7;
        v.z = (d.z + 7) & ~7;
        v.w = (d.w + 7) & ~7;
    }
    int tsum = v.x + v.y + v.z + v.w;
    sdata[tid] = tsum;
    __syncthreads();
    for (int off = 1; off < 256; off <<= 1) {
        int t = (tid >= off) ? sdata[tid - off] : 0;
        __syncthreads();
        sdata[tid] += t;
        __syncthreads();
    }
    if (tid == 255) sbase = atomicAdd(gcount, sdata[255]);
    __syncthreads();
    if (base >= N_NODES) return;
    int excl = sdata[tid] - tsum + sbase;
    int4 o;
    o.x = excl;
    o.y = o.x + v.x;
    o.z = o.y + v.y;
    o.w = o.z + v.z;
    *(int4*)(row_off + base) = o;
    *(int4*)(cursor + base) = o;
    float4 di;
    di.x = rsqrtf((float)(d.x + 1));
    di.y = rsqrtf((float)(d.y + 1));
    di.z = rsqrtf((float)(d.z + 1));
    di.w = rsqrtf((float)(d.w + 1));
    *(float4*)(dinv + base) = di;
}

// ===========================================================================
// XCD-partitioned CSR scatter. 25000 blocks: block b covers edge chunk b>>3
// and processes only edges whose dst partition (dst/12500) == b&7. Since
// consecutive blockIdx round-robins across the 8 XCDs, each ~1.6 MB CSR
// slice is written by exactly one XCD's L2 -> lines written back once
// (R11 showed un-partitioned scatter writes 52 MB for a 12.8 MB region:
// every XCD's L2 acquired every line).
// ===========================================================================
__global__ __launch_bounds__(256) void k_build(const int* __restrict__ ei,
                                               const float* __restrict__ dinv,
                                               int* __restrict__ cursor,
                                               int2* __restrict__ edges) {
    int part = blockIdx.x & 7;
    int e = (blockIdx.x >> 3) * 256 + threadIdx.x;
    if (e >= N_EDGES) return;
    int d = ei[N_EDGES + e];
    if (d / 12500 != part) return;
    int s = ei[e];
    int pos = atomicAdd(&cursor[d], 1);
    edges[pos] = make_int2(s, __float_as_int(dinv[s] * dinv[d]));
}

// ===========================================================================
// Aggregation over fp16 features, fp16 output: one wave per node, lane = col.
// CSR segments padded to x8 (pads are {0,0}: gather row 0 with weight 0).
// ===========================================================================
__global__ __launch_bounds__(256) void k_aggregate(const __half* __restrict__ xin,
                                                   const int* __restrict__ row_off,
                                                   const int* __restrict__ deg,
                                                   const int2* __restrict__ edges,
                                                   const float* __restrict__ dinv,
                                                   __half* __restrict__ out) {
    int lane = threadIdx.x & 63;
    int node = blockIdx.x * 4 + (threadIdx.x >> 6);   // grid = 25000 exact
    float di = dinv[node];
    float acc = __half2float(xin[(size_t)node * DIM + lane]) * (di * di);
    int beg = __builtin_amdgcn_readfirstlane(row_off[node]);
    int lenp = (__builtin_amdgcn_readfirstlane(deg[node]) + 7) & ~7;
    int end = beg + lenp;
    for (int k = beg; k < end; k += 8) {
        int2 e0 = edges[k + 0];
        int2 e1 = edges[k + 1];
        int2 e2 = edges[k + 2];
        int2 e3 = edges[k + 3];
        int2 e4 = edges[k + 4];
        int2 e5 = edges[k + 5];
        int2 e6 = edges[k + 6];
        int2 e7 = edges[k + 7];
        float v0 = __half2float(xin[(size_t)e0.x * DIM + lane]);
        float v1 = __half2float(xin[(size_t)e1.x * DIM + lane]);
        float v2 = __half2float(xin[(size_t)e2.x * DIM + lane]);
        float v3 = __half2float(xin[(size_t)e3.x * DIM + lane]);
        float v4 = __half2float(xin[(size_t)e4.x * DIM + lane]);
        float v5 = __half2float(xin[(size_t)e5.x * DIM + lane]);
        float v6 = __half2float(xin[(size_t)e6.x * DIM + lane]);
        float v7 = __half2float(xin[(size_t)e7.x * DIM + lane]);
        acc = fmaf(__int_as_float(e0.y), v0, acc);
        acc = fmaf(__int_as_float(e1.y), v1, acc);
        acc = fmaf(__int_as_float(e2.y), v2, acc);
        acc = fmaf(__int_as_float(e3.y), v3, acc);
        acc = fmaf(__int_as_float(e4.y), v4, acc);
        acc = fmaf(__int_as_float(e5.y), v5, acc);
        acc = fmaf(__int_as_float(e6.y), v6, acc);
        acc = fmaf(__int_as_float(e7.y), v7, acc);
    }
    out[(size_t)node * DIM + lane] = __float2half(acc);
}

// 64 FMAs of a 4-row x 4-col x 4-k outer-product step (sX stride = LDX)
#define GEMM_STEP(SX, SW)                                                      \
    {                                                                          \
        float4 a0 = *(const float4*)&SX[(r0 + 0) * LDX + k4 * 4];              \
        float4 a1 = *(const float4*)&SX[(r0 + 1) * LDX + k4 * 4];              \
        float4 a2 = *(const float4*)&SX[(r0 + 2) * LDX + k4 * 4];              \
        float4 a3 = *(const float4*)&SX[(r0 + 3) * LDX + k4 * 4];              \
        float4 b0 = *(const float4*)&SW[(k4 * 4 + 0) * 64 + c0];               \
        float4 b1 = *(const float4*)&SW[(k4 * 4 + 1) * 64 + c0];               \
        float4 b2 = *(const float4*)&SW[(k4 * 4 + 2) * 64 + c0];               \
        float4 b3 = *(const float4*)&SW[(k4 * 4 + 3) * 64 + c0];               \
        const float* ap[4] = {&a0.x, &a1.x, &a2.x, &a3.x};                     \
        _Pragma("unroll") for (int i = 0; i < 4; ++i) {                        \
            float x0 = ap[i][0], x1 = ap[i][1], x2 = ap[i][2], x3 = ap[i][3];  \
            acc[i][0] = fmaf(x0, b0.x, acc[i][0]);                             \
            acc[i][1] = fmaf(x0, b0.y, acc[i][1]);                             \
            acc[i][2] = fmaf(x0, b0.z, acc[i][2]);                             \
            acc[i][3] = fmaf(x0, b0.w, acc[i][3]);                             \
            acc[i][0] = fmaf(x1, b1.x, acc[i][0]);                             \
            acc[i][1] = fmaf(x1, b1.y, acc[i][1]);                             \
            acc[i][2] = fmaf(x1, b1.z, acc[i][2]);                             \
            acc[i][3] = fmaf(x1, b1.w, acc[i][3]);                             \
            acc[i][0] = fmaf(x2, b2.x, acc[i][0]);                             \
            acc[i][1] = fmaf(x2, b2.y, acc[i][1]);                             \
            acc[i][2] = fmaf(x2, b2.z, acc[i][2]);                             \
            acc[i][3] = fmaf(x2, b2.w, acc[i][3]);                             \
            acc[i][0] = fmaf(x3, b3.x, acc[i][0]);                             \
            acc[i][1] = fmaf(x3, b3.y, acc[i][1]);                             \
            acc[i][2] = fmaf(x3, b3.z, acc[i][2]);                             \
            acc[i][3] = fmaf(x3, b3.w, acc[i][3]);                             \
        }                                                                      \
    }

// stage one 64-row fp16 tile into fp32 LDS (thread r=tid>>2, q=tid&3)
#define STAGE_H2F(SRCPTR, SXPTR)                                               \
    {                                                                          \
        int r = tid >> 2;                                                      \
        int q = tid & 3;                                                       \
        int row = row0 + r;                                                    \
        float4* dst = (float4*)(SXPTR + r * LDX);                              \
        if (row < N_NODES) {                                                   \
            const uint2* src = (const uint2*)(SRCPTR + (size_t)row * DIM);     \
            _Pragma("unroll") for (int m = 0; m < 4; ++m) {                    \
                uint2 u = src[q + m * 4];                                      \
                float4 f;                                                      \
                f.x = __half2float(__ushort_as_half((unsigned short)(u.x & 0xffff)));       \
                f.y = __half2float(__ushort_as_half((unsigned short)(u.x >> 16)));          \
                f.z = __half2float(__ushort_as_half((unsigned short)(u.y & 0xffff)));       \
                f.w = __half2float(__ushort_as_half((unsigned short)(u.y >> 16)));          \
                dst[q + m * 4] = f;                                            \
            }                                                                  \
        } else {                                                               \
            float4 z = make_float4(0.f, 0.f, 0.f, 0.f);                        \
            _Pragma("unroll") for (int m = 0; m < 4; ++m) dst[q + m * 4] = z;  \
        }                                                                      \
    }

// ===========================================================================
// Register-tiled GEMM + BN + ReLU: fp16 in, fp16 out, fp32 math.
// ===========================================================================
__global__ __launch_bounds__(256) void k_gemm_bn_h(const __half* __restrict__ xin,
                                                   const float* __restrict__ W,
                                                   const float* __restrict__ bias,
                                                   const float* __restrict__ bng,
                                                   const float* __restrict__ bnb,
                                                   const float* __restrict__ bnm,
                                                   const float* __restrict__ bnv,
                                                   __half* __restrict__ out) {
    __shared__ float sW[4096];
    __shared__ float sX[64 * LDX];
    int tid = threadIdx.x;
    int row0 = blockIdx.x * 64;

    for (int i = tid; i < 1024; i += 256)
        ((float4*)sW)[i] = ((const float4*)W)[i];
    STAGE_H2F(xin, sX)
    __syncthreads();

    int cq = tid & 15, rq = tid >> 4;
    int c0 = cq * 4, r0 = rq * 4;
    float acc[4][4];
#pragma unroll
    for (int i = 0; i < 4; ++i)
#pragma unroll
        for (int j = 0; j < 4; ++j) acc[i][j] = 0.f;

#pragma unroll 4
    for (int k4 = 0; k4 < 16; ++k4) GEMM_STEP(sX, sW)

    float4 bv = *(const float4*)&bias[c0];
    float4 g = *(const float4*)&bng[c0];
    float4 bb = *(const float4*)&bnb[c0];
    float4 m = *(const float4*)&bnm[c0];
    float4 vv = *(const float4*)&bnv[c0];
    float A0 = g.x * rsqrtf(vv.x + BN_EPS);
    float A1 = g.y * rsqrtf(vv.y + BN_EPS);
    float A2 = g.z * rsqrtf(vv.z + BN_EPS);
    float A3 = g.w * rsqrtf(vv.w + BN_EPS);
    float B0 = (bv.x - m.x) * A0 + bb.x;
    float B1 = (bv.y - m.y) * A1 + bb.y;
    float B2 = (bv.z - m.z) * A2 + bb.z;
    float B3 = (bv.w - m.w) * A3 + bb.w;
#pragma unroll
    for (int i = 0; i < 4; ++i) {
        int row = row0 + r0 + i;
        if (row >= N_NODES) break;
        unsigned int u0 = __half_as_ushort(__float2half(fmaxf(0.f, fmaf(acc[i][0], A0, B0))));
        unsigned int u1 = __half_as_ushort(__float2half(fmaxf(0.f, fmaf(acc[i][1], A1, B1))));
        unsigned int u2 = __half_as_ushort(__float2half(fmaxf(0.f, fmaf(acc[i][2], A2, B2))));
        unsigned int u3 = __half_as_ushort(__float2half(fmaxf(0.f, fmaf(acc[i][3], A3, B3))));
        *(uint2*)(out + (size_t)row * DIM + c0) = make_uint2(u0 | (u1 << 16), u2 | (u3 << 16));
    }
}

// ===========================================================================
// Tail: out = tanh(x @ W3p + b3p) @ pW2 + pb2; fp16 in, fp32 out.
// ===========================================================================
__global__ __launch_bounds__(256) void k_tail(const __half* __restrict__ xin,
                                              const float* __restrict__ W3p,
                                              const float* __restrict__ b3p,
                                              const float* __restrict__ pW2,
                                              const float* __restrict__ pb2,
                                              float* __restrict__ out) {
    __shared__ float sW1[4096];
    __shared__ float sW2[4096];
    __shared__ float sX[64 * LDX];
    int tid = threadIdx.x;
    int row0 = blockIdx.x * 64;

    for (int i = tid; i < 1024; i += 256) {
        ((float4*)sW1)[i] = ((const float4*)W3p)[i];
        ((float4*)sW2)[i] = ((const float4*)pW2)[i];
    }
    STAGE_H2F(xin, sX)
    __syncthreads();

    int cq = tid & 15, rq = tid >> 4;
    int c0 = cq * 4, r0 = rq * 4;
    float acc[4][4];

    // ---- GEMM 1: sX @ W3p ----
#pragma unroll
    for (int i = 0; i < 4; ++i)
#pragma unroll
        for (int j = 0; j < 4; ++j) acc[i][j] = 0.f;
#pragma unroll 4
    for (int k4 = 0; k4 < 16; ++k4) GEMM_STEP(sX, sW1)
    __syncthreads();

    {
        float4 bv = *(const float4*)&b3p[c0];
#pragma unroll
        for (int i = 0; i < 4; ++i) {
            float4 h;
            h.x = tanhf(acc[i][0] + bv.x);
            h.y = tanhf(acc[i][1] + bv.y);
            h.z = tanhf(acc[i][2] + bv.z);
            h.w = tanhf(acc[i][3] + bv.w);
            *(float4*)&sX[(r0 + i) * LDX + c0] = h;
        }
    }
    __syncthreads();

    // ---- GEMM 2: sX @ pW2 ----
#pragma unroll
    for (int i = 0; i < 4; ++i)
#pragma unroll
        for (int j = 0; j < 4; ++j) acc[i][j] = 0.f;
#pragma unroll 4
    for (int k4 = 0; k4 < 16; ++k4) GEMM_STEP(sX, sW2)

    float4 bv = *(const float4*)&pb2[c0];
#pragma unroll
    for (int i = 0; i < 4; ++i) {
        int row = row0 + r0 + i;
        if (row >= N_NODES) break;
        float4 o;
        o.x = acc[i][0] + bv.x;
        o.y = acc[i][1] + bv.y;
        o.z = acc[i][2] + bv.z;
        o.w = acc[i][3] + bv.w;
        *(float4*)(out + (size_t)row * DIM + c0) = o;
    }
}

// ===========================================================================
extern "C" void kernel_launch(void* const* d_in, const int* in_sizes, int n_in,
                              void* d_out, int out_size, void* d_ws, size_t ws_size,
                              hipStream_t stream) {
    const float* x     = (const float*)d_in[0];
    const int*   ei    = (const int*)d_in[1];
    const float* W1    = (const float*)d_in[2];
    const float* b1    = (const float*)d_in[3];
    const float* W2    = (const float*)d_in[4];
    const float* b2    = (const float*)d_in[5];
    const float* W3    = (const float*)d_in[6];
    const float* b3    = (const float*)d_in[7];
    const float* bn1_g = (const float*)d_in[8];
    const float* bn1_b = (const float*)d_in[9];
    const float* bn1_m = (const float*)d_in[10];
    const float* bn1_v = (const float*)d_in[11];
    const float* bn2_g = (const float*)d_in[12];
    const float* bn2_b = (const float*)d_in[13];
    const float* bn2_m = (const float*)d_in[14];
    const float* bn2_v = (const float*)d_in[15];
    const float* pW1   = (const float*)d_in[16];
    const float* pb1   = (const float*)d_in[17];
    const float* pW2   = (const float*)d_in[18];
    const float* pb2   = (const float*)d_in[19];
    float* out = (float*)d_out;

    // Layout: deg..edges contiguous so ONE memset zeroes deg, gcount, row_off,
    // cursor (overwritten by scan) and all edge pad slots ({0,0} = weight 0).
    char* ws = (char*)d_ws;
    int*    deg     = (int*)ws;                      ws += 100352 * 4;
    int*    gcount  = (int*)ws;                      ws += 4 * 4;
    int*    row_off = (int*)ws;                      ws += 100352 * 4;
    int*    cursor  = (int*)ws;                      ws += 100352 * 4;
    int2*   edges   = (int2*)ws;                     ws += (size_t)EDGE_CAP * 8;
    float*  dinv    = (float*)ws;                    ws += 100352 * 4;
    float*  W3p     = (float*)ws;                    ws += 4096 * 4;
    float*  b3p     = (float*)ws;                    ws += 64 * 4;
    __half* xh      = (__half*)ws;                   ws += (size_t)N_NODES * DIM * 2;
    __half* hbuf    = (__half*)ws;                   ws += (size_t)N_NODES * DIM * 2;
    __half* abuf    = (__half*)ws;                   ws += (size_t)N_NODES * DIM * 2;

    const int blk = 256;
    int gCvt   = 6250;                           // covers 1.6M cvt + 800k count
    int gBuild = 3125 * 8;                       // 8 XCD partitions per chunk
    int gAgg   = N_NODES / 4;                    // 25000 (exact)
    int gTile  = (N_NODES + 63) / 64;            // 1563

    size_t zbytes = (size_t)(100352 * 3 + 4) * 4 + (size_t)EDGE_CAP * 8;
    hipMemsetAsync(deg, 0, zbytes, stream);
    k_cvt_count<<<gCvt, blk, 0, stream>>>(x, xh, ei + N_EDGES, deg);
    k_scan_fuse<<<99, blk, 0, stream>>>(deg, row_off, cursor, dinv, gcount,
                                        W3, b3, pW1, pb1, W3p, b3p);
    k_build<<<gBuild, blk, 0, stream>>>(ei, dinv, cursor, edges);

    // ---- layer 1 ----
    k_aggregate<<<gAgg, blk, 0, stream>>>(xh, row_off, deg, edges, dinv, abuf);
    k_gemm_bn_h<<<gTile, blk, 0, stream>>>(abuf, W1, b1, bn1_g, bn1_b, bn1_m, bn1_v, hbuf);

    // ---- layer 2 ----
    k_aggregate<<<gAgg, blk, 0, stream>>>(hbuf, row_off, deg, edges, dinv, abuf);
    k_gemm_bn_h<<<gTile, blk, 0, stream>>>(abuf, W2, b2, bn2_g, bn2_b, bn2_m, bn2_v, hbuf);

    // ---- layer 3 + fused predictor ----
    k_aggregate<<<gAgg, blk, 0, stream>>>(hbuf, row_off, deg, edges, dinv, abuf);
    k_tail<<<gTile, blk, 0, stream>>>(abuf, W3p, b3p, pW2, pb2, out);
}